// Round 17
// baseline (402.190 us; speedup 1.0000x reference)
//
#include <hip/hip_runtime.h>
#include <hip/hip_bf16.h>

// Sizes
#define NB 128
#define CIN 30
#define HW 15
#define OC 256
#define H1 13   // conv1 out
#define H2 11   // conv2 out
#define NCAPS 3872
#define IND 8
#define OUTD 16
#define CLS 16
#define D1 328
#define D2 192
#define OUTPIX 6750   // 30*15*15
#define NSPLIT 121
#define NPB 32        // 121*32 = 3872 exactly
#define RN 2          // n's per LDS buffer round
#define ROUNDS 16     // NPB/RN

typedef __attribute__((ext_vector_type(8))) short short8_t;
typedef __attribute__((ext_vector_type(4))) float f32x4;
typedef __attribute__((ext_vector_type(4))) unsigned int u32x4;

__device__ inline unsigned bf16rne(float f) {
  unsigned u = __builtin_bit_cast(unsigned, f);
  return (u + 0x7FFF + ((u >> 16) & 1)) >> 16;
}

// bf16 pair (one u32) -> two exact f32
#define BLO(u) __builtin_bit_cast(float, (unsigned)((u) << 16))
#define BHI(u) __builtin_bit_cast(float, (unsigned)((u) & 0xffff0000u))

// ---------------- pack conv1+conv2 weights (merged) -------------------------
__global__ __launch_bounds__(256) void pack_w12_k(const float* __restrict__ w1,
    const float* __restrict__ w2, unsigned short* __restrict__ wpk1,
    unsigned short* __restrict__ wpk) {
  int tid = blockIdx.x * blockDim.x + threadIdx.x;   // 663552
  if (tid < 73728) {
    int j = tid & 7;
    int oc = (tid >> 3) & 255;
    int kc = (tid >> 11) & 3;
    int tap = tid >> 13;
    int ic = kc * 8 + j;
    float v = (ic < CIN) ? w1[((size_t)oc * CIN + ic) * 9 + tap] : 0.f;
    wpk1[tid] = (unsigned short)bf16rne(v);
  } else {
    int t2 = tid - 73728;                // 589824
    int e = t2 & 7;
    int oc = (t2 >> 3) & 255;
    int icchunk = (t2 >> 11) & 31;
    int kykx = t2 >> 16;
    int ic = icchunk * 8 + e;
    wpk[t2] = (unsigned short)bf16rne(w2[((size_t)oc * 256 + ic) * 9 + kykx]);
  }
}

// ---------------- conv1 via bf16 MFMA implicit GEMM + BN partial sums -------
__global__ __launch_bounds__(512, 1) void conv1_mfma_k(
    const float* __restrict__ x, const unsigned short* __restrict__ wpk1,
    const float* __restrict__ bias, float* __restrict__ h,
    float* __restrict__ hsum, float* __restrict__ hsum2) {
  __shared__ char smem[128 * 176 * 4];   // 90112 B; staging uses first 16200 B
  unsigned* hs32 = (unsigned*)smem;      // [pix][18 u32] (36 bf16, 32 data+4 pad)
  int bid = blockIdx.x;                  // 0..255
  int b = bid >> 1;
  int nh = bid & 1;
  int t = threadIdx.x;
  int l = t & 63;
  int wid = t >> 6;

  if (t < 225) {
    const float* xb = x + (size_t)b * (CIN * 225);
#pragma unroll
    for (int icp = 0; icp < 15; icp++) {
      unsigned u0 = bf16rne(xb[(2 * icp) * 225 + t]);
      unsigned u1 = bf16rne(xb[(2 * icp + 1) * 225 + t]);
      hs32[t * 18 + icp] = u0 | (u1 << 16);
    }
    hs32[t * 18 + 15] = 0;               // ic 30,31 zero pad
  }
  __syncthreads();

  int row = l & 15, kc = l >> 4;
  int ocb = nh * 128 + wid * 16;

  int arow[11];
#pragma unroll
  for (int mf = 0; mf < 11; mf++) {
    int m = mf * 16 + row;
    int pix = 0;
    if (m < 169) { int oy = m / 13, ox = m - oy * 13; pix = oy * HW + ox; }
    arow[mf] = pix * 72 + kc * 16;
  }

  f32x4 acc[11];
#pragma unroll
  for (int mf = 0; mf < 11; mf++) acc[mf] = (f32x4){0.f, 0.f, 0.f, 0.f};

  const size_t lanebase = ((size_t)ocb + row) * 8;
  const char* lds_base = (const char*)smem;

#pragma unroll
  for (int tap = 0; tap < 9; tap++) {
    const int ky = tap / 3, kx = tap % 3;
    const int koff = (ky * HW + kx) * 72;
    short8_t bfr = *(const short8_t*)(wpk1 + (size_t)(tap * 4 + kc) * 2048 + lanebase);
#pragma unroll
    for (int mf = 0; mf < 11; mf++) {
      short8_t af = *(const short8_t*)(lds_base + arow[mf] + koff);
      acc[mf] = __builtin_amdgcn_mfma_f32_16x16x32_bf16(af, bfr, acc[mf], 0, 0, 0);
    }
  }

  __syncthreads();
  float* cl = (float*)smem;              // [ocl 128][176 m-pad]
  {
    int ocl = wid * 16 + row;
#pragma unroll
    for (int mf = 0; mf < 11; mf++) {
      int m0 = mf * 16 + kc * 4;
      *(f32x4*)&cl[ocl * 176 + m0] = acc[mf];
    }
  }
  __syncthreads();
  for (int idx = t; idx < 128 * 169; idx += 512) {
    int ocl = idx / 169;
    int m = idx - ocl * 169;
    int oc = nh * 128 + ocl;
    h[((size_t)b * 256 + oc) * 169 + m] = cl[ocl * 176 + m] + bias[oc];
  }
  // BN partial sums per (b, oc): deterministic fixed-order reduction
  {
    int ocl = t >> 2, sub = t & 3;
    float bs = bias[nh * 128 + ocl];
    float s1 = 0.f, s2 = 0.f;
    int m0 = sub * 43, m1 = m0 + 43; if (m1 > 169) m1 = 169;
    for (int m = m0; m < m1; m++) {
      float v = cl[ocl * 176 + m] + bs;
      s1 += v; s2 += v * v;
    }
    s1 += __shfl_xor(s1, 1); s2 += __shfl_xor(s2, 1);
    s1 += __shfl_xor(s1, 2); s2 += __shfl_xor(s2, 2);
    if (sub == 0) {
      hsum[b * 256 + nh * 128 + ocl] = s1;
      hsum2[b * 256 + nh * 128 + ocl] = s2;
    }
  }
}

// ---------------- BN finalize: reduce 128 b-partials per channel ------------
__global__ __launch_bounds__(128) void bn_finalize_k(const float* __restrict__ hsum,
    const float* __restrict__ hsum2, float* __restrict__ mean, float* __restrict__ istd) {
  int c = blockIdx.x * 128 + threadIdx.x;   // 2 blocks x 128
  float s = 0.f, s2 = 0.f;
  for (int b = 0; b < NB; b++) {
    s += hsum[b * 256 + c];
    s2 += hsum2[b * 256 + c];
  }
  const float inv_n = 1.0f / (NB * H1 * H1);
  float m = s * inv_n;
  float v = s2 * inv_n - m * m;
  mean[c] = m;
  istd[c] = rsqrtf(v + 1e-5f);
}

// ---------------- conv2 via bf16 MFMA (BN+relu fused in; squash fused out) --
__global__ __launch_bounds__(512, 1) void conv2_mfma_k(
    const float* __restrict__ h, const unsigned short* __restrict__ wpk,
    const float* __restrict__ bias, float* __restrict__ caps,
    const float* __restrict__ mean, const float* __restrict__ istd,
    const float* __restrict__ gamma, const float* __restrict__ beta) {
  __shared__ char smem[169 * 544];       // 91936 B; reused for C transpose
  unsigned* hs32 = (unsigned*)smem;      // [pix][136] u32  (272 bf16, 16 pad)
  int bid = blockIdx.x;                  // 0..255
  int b = bid >> 1;
  int nh = bid & 1;                      // oc half
  int t = threadIdx.x;
  int l = t & 63, wid = t >> 6;

  {
    const float* hb = h + (size_t)b * 256 * 169;
    for (int icp = wid; icp < 128; icp += 8) {
      const float* s0 = hb + (size_t)icp * 2 * 169;
      int c0i = icp * 2, c1i = icp * 2 + 1;
      float a0 = istd[c0i] * gamma[c0i], sh0 = beta[c0i] - mean[c0i] * a0;
      float a1 = istd[c1i] * gamma[c1i], sh1 = beta[c1i] - mean[c1i] * a1;
#pragma unroll
      for (int pb = 0; pb < 3; pb++) {
        int pix = pb * 64 + l;
        if (pix < 169) {
          float v0 = fmaxf(fmaf(s0[pix], a0, sh0), 0.f);
          float v1 = fmaxf(fmaf(s0[169 + pix], a1, sh1), 0.f);
          hs32[pix * 136 + icp] = bf16rne(v0) | (bf16rne(v1) << 16);
        }
      }
    }
  }
  __syncthreads();

  int wm = wid & 1;        // m offset wm*64
  int wn = wid >> 1;       // n offset wn*32
  int row = l & 15, kc = l >> 4;
  int ocb = nh * 128 + wn * 32;

  int abase[4];
#pragma unroll
  for (int mf = 0; mf < 4; mf++) {
    int m = wm * 64 + mf * 16 + row;
    int p0 = (m < 121) ? ((m / 11) * 13 + (m % 11)) : 0;
    abase[mf] = p0 * 544 + kc * 16;
  }

  f32x4 acc[4][2];
#pragma unroll
  for (int mf = 0; mf < 4; mf++)
#pragma unroll
    for (int nf = 0; nf < 2; nf++)
      acc[mf][nf] = (f32x4){0.f, 0.f, 0.f, 0.f};

  const size_t lanebase = ((size_t)kc * 256 + ocb + row) * 8;
  const char* lds_base = (const char*)smem;

  for (int ky = 0; ky < 3; ky++) {
    for (int kx = 0; kx < 3; kx++) {
      int r = ky * 3 + kx;
      int koff = (ky * 13 + kx) * 544;
#pragma unroll
      for (int ks = 0; ks < 8; ks++) {
        short8_t bfr[2];
#pragma unroll
        for (int nf = 0; nf < 2; nf++) {
          size_t idx = lanebase + (size_t)(r * 32 + ks * 4) * 2048 + nf * 128;
          bfr[nf] = *(const short8_t*)(wpk + idx);
        }
        short8_t af[4];
#pragma unroll
        for (int mf = 0; mf < 4; mf++)
          af[mf] = *(const short8_t*)(lds_base + (abase[mf] + koff + ks * 64));
#pragma unroll
        for (int mf = 0; mf < 4; mf++)
#pragma unroll
          for (int nf = 0; nf < 2; nf++)
            acc[mf][nf] = __builtin_amdgcn_mfma_f32_16x16x32_bf16(
                af[mf], bfr[nf], acc[mf][nf], 0, 0, 0);
      }
    }
  }

  __syncthreads();
  float* cl = (float*)smem;              // [ocl 0..127][132 m-pad]
#pragma unroll
  for (int nf = 0; nf < 2; nf++) {
    int ocl = wn * 32 + nf * 16 + row;
#pragma unroll
    for (int mf = 0; mf < 4; mf++) {
      int m0 = wm * 64 + mf * 16 + kc * 4;
      f32x4 v = acc[mf][nf];
      *(f32x4*)&cl[ocl * 132 + m0] = v;
    }
  }
  __syncthreads();
  // fused squash: groups of 8 over flat [128 oc][121 pix] (+bias) -> caps
  for (int g = t; g < 1936; g += 512) {
    int base = g * 8;
    float v[8];
    float n2 = 0.f;
#pragma unroll
    for (int e = 0; e < 8; e++) {
      int idx = base + e;
      int q = idx / 121, rmd = idx - q * 121;
      float val = cl[q * 132 + rmd] + bias[nh * 128 + q];
      v[e] = val;
      n2 += val * val;
    }
    float nrm = sqrtf(n2);
    float scale = n2 / (1.f + n2) / (nrm + 1e-8f);
    float4 o0 = {v[0] * scale, v[1] * scale, v[2] * scale, v[3] * scale};
    float4 o1 = {v[4] * scale, v[5] * scale, v[6] * scale, v[7] * scale};
    float4* dst = (float4*)(caps + (((size_t)b * NCAPS) + nh * 1936 + g) * 8);
    dst[0] = o0; dst[1] = o1;
  }
}

// ---------------- pack caps_w: cw[o][n][i][j] -> Wp16[n][o][j][i] bf16 ------
__global__ __launch_bounds__(256) void pack_cw_k(const float* __restrict__ cw,
    unsigned short* __restrict__ Wp16) {
  int idx = blockIdx.x * blockDim.x + threadIdx.x;   // 7929856 = 3872*2048 exact
  int i = idx & 15;
  int j = (idx >> 4) & 7;
  int o = (idx >> 7) & 15;
  int n = idx >> 11;
  Wp16[idx] = (unsigned short)bf16rne(cw[(((size_t)o * NCAPS + n) * 16 + i) * 8 + j]);
}

// ---------------- routing pass v13: 1 b/thread, 968 blocks (2x waves/CU) ----
// block = (split 0..120 x btile 0..7): 256 thr = 16 b x 16 o, one b each.
// Same bf16-W LDS staging as r12 champion; spart traffic unchanged; caps
// FETCH doubles (32MB, ~4us HBM). Latency-bound at 1.9 waves/SIMD -> 3.8.
__global__ __launch_bounds__(256) void route_k(const float* __restrict__ caps,
    const unsigned short* __restrict__ Wp16, const float* __restrict__ osum,
    float* __restrict__ spart) {
  __shared__ unsigned short wl[2][RN * 2176];   // 17408 B
  int id = blockIdx.x;                     // 0..967
  int xcd = id & 7;                        // bijective: 968 = 8*121
  int lin = xcd * 121 + (id >> 3);
  int split = lin >> 3;                    // 0..120
  int btile = lin & 7;                     // 0..7
  int t = threadIdx.x;                     // 0..255
  int o = t & 15;
  int bp = t >> 4;                         // 0..15
  int b0 = btile * 16 + bp;                // this thread: one b

  const float* opa = osum + (b0 * 16 + o) * 16;
  f32x4 oa0 = *(const f32x4*)(opa);
  f32x4 oa1 = *(const f32x4*)(opa + 4);
  f32x4 oa2 = *(const f32x4*)(opa + 8);
  f32x4 oa3 = *(const f32x4*)(opa + 12);
  f32x4 sA0 = {0.f,0.f,0.f,0.f}, sA1 = {0.f,0.f,0.f,0.f};
  f32x4 sA2 = {0.f,0.f,0.f,0.f}, sA3 = {0.f,0.f,0.f,0.f};

  int nbeg = split * NPB;
  const u32x4* src = (const u32x4*)(Wp16 + (size_t)nbeg * 2048);  // 16B chunks

  // staging dest for chunk e: halfs (e>>8)*2176 + ((e>>4)&15)*136 + (e&15)*8
  int e0 = t, e1 = t + 256;
  int d0 = (e0 >> 8) * 2176 + ((e0 >> 4) & 15) * 136 + (e0 & 15) * 8;
  int d1 = (e1 >> 8) * 2176 + ((e1 >> 4) & 15) * 136 + (e1 & 15) * 8;

  // prologue: stage round 0 into buf 0
  {
    u32x4 v0 = src[e0], v1 = src[e1];
    *(u32x4*)&wl[0][d0] = v0;
    *(u32x4*)&wl[0][d1] = v1;
  }
  __syncthreads();

  for (int r = 0; r < ROUNDS; r++) {
    u32x4 nv0, nv1;
    if (r < ROUNDS - 1) {
      const u32x4* s2 = src + (r + 1) * 512;
      nv0 = s2[e0]; nv1 = s2[e1];
    }
    const unsigned short* wlb = wl[r & 1];
#pragma unroll
    for (int nl = 0; nl < RN; nl++) {
      int n = nbeg + r * RN + nl;
      const float4* cpa = (const float4*)(caps + ((size_t)b0 * NCAPS + n) * 8);
      float4 cqa0 = cpa[0], cqa1 = cpa[1];
      float caA[8] = {cqa0.x, cqa0.y, cqa0.z, cqa0.w, cqa1.x, cqa1.y, cqa1.z, cqa1.w};
      const unsigned short* wp = wlb + nl * 2176 + o * 136;
      f32x4 xa0 = {0.f,0.f,0.f,0.f}, xa1 = {0.f,0.f,0.f,0.f};
      f32x4 xa2 = {0.f,0.f,0.f,0.f}, xa3 = {0.f,0.f,0.f,0.f};
#pragma unroll
      for (int j = 0; j < 8; j++) {
        u32x4 wA = *(const u32x4*)(wp + j * 16);
        u32x4 wB = *(const u32x4*)(wp + j * 16 + 8);
        f32x4 w0 = {BLO(wA.x), BHI(wA.x), BLO(wA.y), BHI(wA.y)};
        f32x4 w1 = {BLO(wA.z), BHI(wA.z), BLO(wA.w), BHI(wA.w)};
        f32x4 w2 = {BLO(wB.x), BHI(wB.x), BLO(wB.y), BHI(wB.y)};
        f32x4 w3 = {BLO(wB.z), BHI(wB.z), BLO(wB.w), BHI(wB.w)};
        float cjA = caA[j];
        xa0 += w0 * cjA; xa1 += w1 * cjA; xa2 += w2 * cjA; xa3 += w3 * cjA;
      }
      f32x4 pA = oa0 * xa0 + oa1 * xa1 + oa2 * xa2 + oa3 * xa3;
      float blogA = (pA.x + pA.y) + (pA.z + pA.w);
      // softmax over o without max-subtract (shift-invariant; |blog| small)
      float eA = __expf(blogA);
      float ssA = eA;
      ssA += __shfl_xor(ssA, 1);
      ssA += __shfl_xor(ssA, 2);
      ssA += __shfl_xor(ssA, 4);
      ssA += __shfl_xor(ssA, 8);
      float ccA = eA * __builtin_amdgcn_rcpf(ssA);
      sA0 += xa0 * ccA; sA1 += xa1 * ccA; sA2 += xa2 * ccA; sA3 += xa3 * ccA;
    }
    if (r < ROUNDS - 1) {
      unsigned short* dst = wl[(r + 1) & 1];
      *(u32x4*)&dst[d0] = nv0;
      *(u32x4*)&dst[d1] = nv1;
      __syncthreads();
    }
  }
  float* spA = spart + (((size_t)split * NB + b0) * 16 + o) * 16;
  *(f32x4*)spA = sA0; *(f32x4*)(spA + 4) = sA1;
  *(f32x4*)(spA + 8) = sA2; *(f32x4*)(spA + 12) = sA3;
}

// ---------------- combine partials + squash + osum update -------------------
__global__ __launch_bounds__(256) void combine_squash_k(const float* __restrict__ spart,
    float* __restrict__ osum, float* __restrict__ outbuf, const float* __restrict__ y,
    float* __restrict__ masked, float* __restrict__ length_out, int last) {
  int tid = blockIdx.x * blockDim.x + threadIdx.x;   // 32768 = 128*16*16
  int i = tid & 15;
  int o = (tid >> 4) & 15;
  int b = tid >> 8;
  float a0 = 0.f, a1 = 0.f, a2 = 0.f, a3 = 0.f;
  int k = 0;
  for (; k + 4 <= NSPLIT; k += 4) {
    a0 += spart[(size_t)k * 32768 + tid];
    a1 += spart[(size_t)(k + 1) * 32768 + tid];
    a2 += spart[(size_t)(k + 2) * 32768 + tid];
    a3 += spart[(size_t)(k + 3) * 32768 + tid];
  }
  float s = (a0 + a1) + (a2 + a3);
  for (; k < NSPLIT; k++) s += spart[(size_t)k * 32768 + tid];
  float n2 = s * s;
#pragma unroll
  for (int d = 1; d < 16; d <<= 1) n2 += __shfl_xor(n2, d);
  float nrm = sqrtf(n2);
  float scale = n2 / (1.f + n2) / (nrm + 1e-8f);
  float ov = scale * s;
  outbuf[tid] = ov;
  osum[tid] += ov;
  if (last) {
    masked[tid] = ov * y[b * 16 + o];
    if (i == 0) length_out[b * 16 + o] = scale * nrm;
  }
}

// ---------------- decoder -----------------------------------------------------
__global__ __launch_bounds__(256) void dec1_k(const float* __restrict__ masked,
    const float* __restrict__ w1, const float* __restrict__ b1, float* __restrict__ r1) {
  int tid = blockIdx.x * blockDim.x + threadIdx.x;
  if (tid >= NB * D1) return;
  int j = tid % D1;
  int b = tid / D1;
  const float* mp = masked + b * 256;
  float acc = b1[j];
  for (int k = 0; k < 256; k++) acc += mp[k] * w1[k * D1 + j];
  r1[tid] = 1.f / (1.f + __expf(-acc));
}

__global__ __launch_bounds__(256) void dec2_k(const float* __restrict__ r1,
    const float* __restrict__ w2, const float* __restrict__ b2, float* __restrict__ r2) {
  int tid = blockIdx.x * blockDim.x + threadIdx.x;
  if (tid >= NB * D2) return;
  int j = tid % D2;
  int b = tid / D2;
  const float* rp = r1 + b * D1;
  float acc = b2[j];
  for (int k = 0; k < D1; k++) acc += rp[k] * w2[k * D2 + j];
  r2[tid] = 1.f / (1.f + __expf(-acc));
}

__global__ __launch_bounds__(256) void dec3_k(const float* __restrict__ r2,
    const float* __restrict__ w3, const float* __restrict__ b3, float* __restrict__ recon) {
  __shared__ float r2s[D2 * 64];
  int mt = blockIdx.x, bh = blockIdx.y;
  int t = threadIdx.x;
  int b0 = bh * 64;
  for (int idx = t; idx < D2 * 64; idx += 256) {
    int bb = idx / D2, k = idx - bb * D2;
    r2s[k * 64 + bb] = r2[(b0 + bb) * D2 + k];
  }
  __syncthreads();
  int moff = t & 63, bg = t >> 6;
  int m = mt * 64 + moff;
  if (m >= OUTPIX) return;
  float acc[16];
#pragma unroll
  for (int q = 0; q < 16; q++) acc[q] = 0.f;
  for (int k = 0; k < D2; k++) {
    float wv = w3[k * OUTPIX + m];
    const float4* r4 = (const float4*)&r2s[k * 64 + bg * 16];
#pragma unroll
    for (int v = 0; v < 4; v++) {
      float4 rv = r4[v];
      acc[v * 4 + 0] += wv * rv.x;
      acc[v * 4 + 1] += wv * rv.y;
      acc[v * 4 + 2] += wv * rv.z;
      acc[v * 4 + 3] += wv * rv.w;
    }
  }
  float bias = b3[m];
#pragma unroll
  for (int q = 0; q < 16; q++) {
    int b = b0 + bg * 16 + q;
    recon[(size_t)b * OUTPIX + m] = acc[q] + bias;
  }
}

extern "C" void kernel_launch(void* const* d_in, const int* in_sizes, int n_in,
                              void* d_out, int out_size, void* d_ws, size_t ws_size,
                              hipStream_t stream) {
  const float* x      = (const float*)d_in[0];
  const float* y      = (const float*)d_in[1];
  const float* conv1w = (const float*)d_in[2];
  const float* conv1b = (const float*)d_in[3];
  const float* gamma  = (const float*)d_in[4];
  const float* beta   = (const float*)d_in[5];
  const float* conv2w = (const float*)d_in[6];
  const float* conv2b = (const float*)d_in[7];
  const float* capsw  = (const float*)d_in[8];
  const float* w1     = (const float*)d_in[9];
  const float* b1     = (const float*)d_in[10];
  const float* w2     = (const float*)d_in[11];
  const float* b2     = (const float*)d_in[12];
  const float* w3     = (const float*)d_in[13];
  const float* b3     = (const float*)d_in[14];

  float* ws = (float*)d_ws;
  float* h      = ws;                    // 128*256*169   = 5537792 (dead after conv2)
  float* p      = h + 5537792;           // 3964928 (unused; kept for layout)
  float* caps   = p + 3964928;           // 128*3872*8    = 3964928
  float* mean   = caps + 3964928;        // 256
  float* istd   = mean + 256;            // 256
  float* osum   = istd + 256;            // 32768
  float* spart  = osum + 32768;          // 121*32768     = 3964928
  float* outb   = spart + 3964928;       // 32768
  float* masked = outb + 32768;          // 32768
  float* r1     = masked + 32768;        // 128*328 = 41984
  float* r2     = r1 + 41984;            // 128*192 = 24576
  unsigned short* wpk = (unsigned short*)(r2 + 24576);   // 589824 bf16
  unsigned short* wpk1 = wpk + 589824;   // 73728 bf16
  // Wp16 aliases h region (dead after conv2): 7929856 halfs = 3964928 floats
  unsigned short* Wp16 = (unsigned short*)ws;
  // hsum/hsum2 use spart region (free until routing)
  float* hsum  = spart;                  // 32768
  float* hsum2 = spart + 32768;          // 32768

  float* length_out = (float*)d_out;           // 2048
  float* recon      = (float*)d_out + 2048;    // 864000

  // conv stem (both convs via MFMA; BN fused; squash fused into conv2)
  pack_w12_k<<<(73728 + 589824) / 256, 256, 0, stream>>>(conv1w, conv2w, wpk1, wpk);
  conv1_mfma_k<<<256, 512, 0, stream>>>(x, wpk1, conv1b, h, hsum, hsum2);
  bn_finalize_k<<<2, 128, 0, stream>>>(hsum, hsum2, mean, istd);
  conv2_mfma_k<<<256, 512, 0, stream>>>(h, wpk, conv2b, caps, mean, istd, gamma, beta);

  // h dead now -> pack caps_w (bf16) into its region (exact grid: 3872*2048)
  pack_cw_k<<<7929856 / 256, 256, 0, stream>>>(capsw, Wp16);

  // dynamic routing (3 iterations), osum = sum of previous outs
  hipMemsetAsync(osum, 0, 32768 * sizeof(float), stream);
  for (int it = 0; it < 3; ++it) {
    route_k<<<968, 256, 0, stream>>>(caps, Wp16, osum, spart);
    combine_squash_k<<<128, 256, 0, stream>>>(spart, osum, outb, y, masked,
                                              length_out, it == 2 ? 1 : 0);
  }

  // decoder
  dec1_k<<<(NB * D1 + 255) / 256, 256, 0, stream>>>(masked, w1, b1, r1);
  dec2_k<<<(NB * D2 + 255) / 256, 256, 0, stream>>>(r1, w2, b2, r2);
  dec3_k<<<dim3((OUTPIX + 63) / 64, 2), 256, 0, stream>>>(r2, w3, b3, recon);
}

// Round 18
// 373.364 us; speedup vs baseline: 1.0772x; 1.0772x over previous
//
#include <hip/hip_runtime.h>
#include <hip/hip_bf16.h>

// Sizes
#define NB 128
#define CIN 30
#define HW 15
#define OC 256
#define H1 13   // conv1 out
#define H2 11   // conv2 out
#define NCAPS 3872
#define IND 8
#define OUTD 16
#define CLS 16
#define D1 328
#define D2 192
#define OUTPIX 6750   // 30*15*15
#define NSPLIT 121
#define NPB 32        // 121*32 = 3872 exactly
#define RN 2          // n's per LDS buffer round
#define ROUNDS 16     // NPB/RN

typedef __attribute__((ext_vector_type(8))) short short8_t;
typedef __attribute__((ext_vector_type(4))) float f32x4;
typedef __attribute__((ext_vector_type(4))) unsigned int u32x4;

__device__ inline unsigned bf16rne(float f) {
  unsigned u = __builtin_bit_cast(unsigned, f);
  return (u + 0x7FFF + ((u >> 16) & 1)) >> 16;
}

// bf16 pair (one u32) -> two exact f32
#define BLO(u) __builtin_bit_cast(float, (unsigned)((u) << 16))
#define BHI(u) __builtin_bit_cast(float, (unsigned)((u) & 0xffff0000u))

// ---------------- pack conv1+conv2 weights (merged) -------------------------
__global__ __launch_bounds__(256) void pack_w12_k(const float* __restrict__ w1,
    const float* __restrict__ w2, unsigned short* __restrict__ wpk1,
    unsigned short* __restrict__ wpk) {
  int tid = blockIdx.x * blockDim.x + threadIdx.x;   // 663552
  if (tid < 73728) {
    int j = tid & 7;
    int oc = (tid >> 3) & 255;
    int kc = (tid >> 11) & 3;
    int tap = tid >> 13;
    int ic = kc * 8 + j;
    float v = (ic < CIN) ? w1[((size_t)oc * CIN + ic) * 9 + tap] : 0.f;
    wpk1[tid] = (unsigned short)bf16rne(v);
  } else {
    int t2 = tid - 73728;                // 589824
    int e = t2 & 7;
    int oc = (t2 >> 3) & 255;
    int icchunk = (t2 >> 11) & 31;
    int kykx = t2 >> 16;
    int ic = icchunk * 8 + e;
    wpk[t2] = (unsigned short)bf16rne(w2[((size_t)oc * 256 + ic) * 9 + kykx]);
  }
}

// ---------------- conv1 via bf16 MFMA implicit GEMM + BN partial sums -------
__global__ __launch_bounds__(512, 1) void conv1_mfma_k(
    const float* __restrict__ x, const unsigned short* __restrict__ wpk1,
    const float* __restrict__ bias, float* __restrict__ h,
    float* __restrict__ hsum, float* __restrict__ hsum2) {
  __shared__ char smem[128 * 176 * 4];   // 90112 B; staging uses first 16200 B
  unsigned* hs32 = (unsigned*)smem;      // [pix][18 u32] (36 bf16, 32 data+4 pad)
  int bid = blockIdx.x;                  // 0..255
  int b = bid >> 1;
  int nh = bid & 1;
  int t = threadIdx.x;
  int l = t & 63;
  int wid = t >> 6;

  if (t < 225) {
    const float* xb = x + (size_t)b * (CIN * 225);
#pragma unroll
    for (int icp = 0; icp < 15; icp++) {
      unsigned u0 = bf16rne(xb[(2 * icp) * 225 + t]);
      unsigned u1 = bf16rne(xb[(2 * icp + 1) * 225 + t]);
      hs32[t * 18 + icp] = u0 | (u1 << 16);
    }
    hs32[t * 18 + 15] = 0;               // ic 30,31 zero pad
  }
  __syncthreads();

  int row = l & 15, kc = l >> 4;
  int ocb = nh * 128 + wid * 16;

  int arow[11];
#pragma unroll
  for (int mf = 0; mf < 11; mf++) {
    int m = mf * 16 + row;
    int pix = 0;
    if (m < 169) { int oy = m / 13, ox = m - oy * 13; pix = oy * HW + ox; }
    arow[mf] = pix * 72 + kc * 16;
  }

  f32x4 acc[11];
#pragma unroll
  for (int mf = 0; mf < 11; mf++) acc[mf] = (f32x4){0.f, 0.f, 0.f, 0.f};

  const size_t lanebase = ((size_t)ocb + row) * 8;
  const char* lds_base = (const char*)smem;

#pragma unroll
  for (int tap = 0; tap < 9; tap++) {
    const int ky = tap / 3, kx = tap % 3;
    const int koff = (ky * HW + kx) * 72;
    short8_t bfr = *(const short8_t*)(wpk1 + (size_t)(tap * 4 + kc) * 2048 + lanebase);
#pragma unroll
    for (int mf = 0; mf < 11; mf++) {
      short8_t af = *(const short8_t*)(lds_base + arow[mf] + koff);
      acc[mf] = __builtin_amdgcn_mfma_f32_16x16x32_bf16(af, bfr, acc[mf], 0, 0, 0);
    }
  }

  __syncthreads();
  float* cl = (float*)smem;              // [ocl 128][176 m-pad]
  {
    int ocl = wid * 16 + row;
#pragma unroll
    for (int mf = 0; mf < 11; mf++) {
      int m0 = mf * 16 + kc * 4;
      *(f32x4*)&cl[ocl * 176 + m0] = acc[mf];
    }
  }
  __syncthreads();
  for (int idx = t; idx < 128 * 169; idx += 512) {
    int ocl = idx / 169;
    int m = idx - ocl * 169;
    int oc = nh * 128 + ocl;
    h[((size_t)b * 256 + oc) * 169 + m] = cl[ocl * 176 + m] + bias[oc];
  }
  // BN partial sums per (b, oc): deterministic fixed-order reduction
  {
    int ocl = t >> 2, sub = t & 3;
    float bs = bias[nh * 128 + ocl];
    float s1 = 0.f, s2 = 0.f;
    int m0 = sub * 43, m1 = m0 + 43; if (m1 > 169) m1 = 169;
    for (int m = m0; m < m1; m++) {
      float v = cl[ocl * 176 + m] + bs;
      s1 += v; s2 += v * v;
    }
    s1 += __shfl_xor(s1, 1); s2 += __shfl_xor(s2, 1);
    s1 += __shfl_xor(s1, 2); s2 += __shfl_xor(s2, 2);
    if (sub == 0) {
      hsum[b * 256 + nh * 128 + ocl] = s1;
      hsum2[b * 256 + nh * 128 + ocl] = s2;
    }
  }
}

// ---------------- BN finalize: reduce 128 b-partials per channel ------------
__global__ __launch_bounds__(128) void bn_finalize_k(const float* __restrict__ hsum,
    const float* __restrict__ hsum2, float* __restrict__ mean, float* __restrict__ istd) {
  int c = blockIdx.x * 128 + threadIdx.x;   // 2 blocks x 128
  float s = 0.f, s2 = 0.f;
  for (int b = 0; b < NB; b++) {
    s += hsum[b * 256 + c];
    s2 += hsum2[b * 256 + c];
  }
  const float inv_n = 1.0f / (NB * H1 * H1);
  float m = s * inv_n;
  float v = s2 * inv_n - m * m;
  mean[c] = m;
  istd[c] = rsqrtf(v + 1e-5f);
}

// ---------------- conv2 via bf16 MFMA (BN+relu fused in; squash fused out) --
__global__ __launch_bounds__(512, 1) void conv2_mfma_k(
    const float* __restrict__ h, const unsigned short* __restrict__ wpk,
    const float* __restrict__ bias, float* __restrict__ caps,
    const float* __restrict__ mean, const float* __restrict__ istd,
    const float* __restrict__ gamma, const float* __restrict__ beta) {
  __shared__ char smem[169 * 544];       // 91936 B; reused for C transpose
  unsigned* hs32 = (unsigned*)smem;      // [pix][136] u32  (272 bf16, 16 pad)
  int bid = blockIdx.x;                  // 0..255
  int b = bid >> 1;
  int nh = bid & 1;                      // oc half
  int t = threadIdx.x;
  int l = t & 63, wid = t >> 6;

  {
    const float* hb = h + (size_t)b * 256 * 169;
    for (int icp = wid; icp < 128; icp += 8) {
      const float* s0 = hb + (size_t)icp * 2 * 169;
      int c0i = icp * 2, c1i = icp * 2 + 1;
      float a0 = istd[c0i] * gamma[c0i], sh0 = beta[c0i] - mean[c0i] * a0;
      float a1 = istd[c1i] * gamma[c1i], sh1 = beta[c1i] - mean[c1i] * a1;
#pragma unroll
      for (int pb = 0; pb < 3; pb++) {
        int pix = pb * 64 + l;
        if (pix < 169) {
          float v0 = fmaxf(fmaf(s0[pix], a0, sh0), 0.f);
          float v1 = fmaxf(fmaf(s0[169 + pix], a1, sh1), 0.f);
          hs32[pix * 136 + icp] = bf16rne(v0) | (bf16rne(v1) << 16);
        }
      }
    }
  }
  __syncthreads();

  int wm = wid & 1;        // m offset wm*64
  int wn = wid >> 1;       // n offset wn*32
  int row = l & 15, kc = l >> 4;
  int ocb = nh * 128 + wn * 32;

  int abase[4];
#pragma unroll
  for (int mf = 0; mf < 4; mf++) {
    int m = wm * 64 + mf * 16 + row;
    int p0 = (m < 121) ? ((m / 11) * 13 + (m % 11)) : 0;
    abase[mf] = p0 * 544 + kc * 16;
  }

  f32x4 acc[4][2];
#pragma unroll
  for (int mf = 0; mf < 4; mf++)
#pragma unroll
    for (int nf = 0; nf < 2; nf++)
      acc[mf][nf] = (f32x4){0.f, 0.f, 0.f, 0.f};

  const size_t lanebase = ((size_t)kc * 256 + ocb + row) * 8;
  const char* lds_base = (const char*)smem;

  for (int ky = 0; ky < 3; ky++) {
    for (int kx = 0; kx < 3; kx++) {
      int r = ky * 3 + kx;
      int koff = (ky * 13 + kx) * 544;
#pragma unroll
      for (int ks = 0; ks < 8; ks++) {
        short8_t bfr[2];
#pragma unroll
        for (int nf = 0; nf < 2; nf++) {
          size_t idx = lanebase + (size_t)(r * 32 + ks * 4) * 2048 + nf * 128;
          bfr[nf] = *(const short8_t*)(wpk + idx);
        }
        short8_t af[4];
#pragma unroll
        for (int mf = 0; mf < 4; mf++)
          af[mf] = *(const short8_t*)(lds_base + (abase[mf] + koff + ks * 64));
#pragma unroll
        for (int mf = 0; mf < 4; mf++)
#pragma unroll
          for (int nf = 0; nf < 2; nf++)
            acc[mf][nf] = __builtin_amdgcn_mfma_f32_16x16x32_bf16(
                af[mf], bfr[nf], acc[mf][nf], 0, 0, 0);
      }
    }
  }

  __syncthreads();
  float* cl = (float*)smem;              // [ocl 0..127][132 m-pad]
#pragma unroll
  for (int nf = 0; nf < 2; nf++) {
    int ocl = wn * 32 + nf * 16 + row;
#pragma unroll
    for (int mf = 0; mf < 4; mf++) {
      int m0 = wm * 64 + mf * 16 + kc * 4;
      f32x4 v = acc[mf][nf];
      *(f32x4*)&cl[ocl * 132 + m0] = v;
    }
  }
  __syncthreads();
  // fused squash: groups of 8 over flat [128 oc][121 pix] (+bias) -> caps
  for (int g = t; g < 1936; g += 512) {
    int base = g * 8;
    float v[8];
    float n2 = 0.f;
#pragma unroll
    for (int e = 0; e < 8; e++) {
      int idx = base + e;
      int q = idx / 121, rmd = idx - q * 121;
      float val = cl[q * 132 + rmd] + bias[nh * 128 + q];
      v[e] = val;
      n2 += val * val;
    }
    float nrm = sqrtf(n2);
    float scale = n2 / (1.f + n2) / (nrm + 1e-8f);
    float4 o0 = {v[0] * scale, v[1] * scale, v[2] * scale, v[3] * scale};
    float4 o1 = {v[4] * scale, v[5] * scale, v[6] * scale, v[7] * scale};
    float4* dst = (float4*)(caps + (((size_t)b * NCAPS) + nh * 1936 + g) * 8);
    dst[0] = o0; dst[1] = o1;
  }
}

// ---------------- pack caps_w: cw[o][n][i][j] -> Wp16[n][o][j][i] bf16 ------
__global__ __launch_bounds__(256) void pack_cw_k(const float* __restrict__ cw,
    unsigned short* __restrict__ Wp16) {
  int idx = blockIdx.x * blockDim.x + threadIdx.x;   // 7929856 = 3872*2048 exact
  int i = idx & 15;
  int j = (idx >> 4) & 7;
  int o = (idx >> 7) & 15;
  int n = idx >> 11;
  Wp16[idx] = (unsigned short)bf16rne(cw[(((size_t)o * NCAPS + n) * 16 + i) * 8 + j]);
}

// ---------------- routing pass (champion v10 + uniform-it0 fast path) -------
// block = (split 0..120 x btile 0..3): 256 thr = 16 b-pairs x 16 o, 2 b/thr.
// uniform=1 (iteration 0): blog==0 => softmax coeff == 1/16 exactly; skip
// blog-dot, exp, shuffles, rcp. Bitwise-identical to the full path at it=0.
__global__ __launch_bounds__(256) void route_k(const float* __restrict__ caps,
    const unsigned short* __restrict__ Wp16, const float* __restrict__ osum,
    float* __restrict__ spart, int uniform) {
  __shared__ unsigned short wl[2][RN * 2176];   // 17408 B
  int id = blockIdx.x;                     // 0..483
  // bijective chunked XCD swizzle (484 = 4 chunks of 61 + 4 of 60):
  int xcd = id & 7;
  int lin = (xcd < 4 ? xcd * 61 : 244 + (xcd - 4) * 60) + (id >> 3);
  int split = lin >> 2;                    // 0..120
  int btile = lin & 3;                     // 0..3
  int t = threadIdx.x;                     // 0..255
  int o = t & 15;
  int bp = t >> 4;                         // 0..15
  int b0 = btile * 32 + bp * 2;            // this thread: b0 and b0+1

  const float* opa = osum + (b0 * 16 + o) * 16;
  f32x4 oa0 = *(const f32x4*)(opa);
  f32x4 oa1 = *(const f32x4*)(opa + 4);
  f32x4 oa2 = *(const f32x4*)(opa + 8);
  f32x4 oa3 = *(const f32x4*)(opa + 12);
  const float* opb = opa + 256;
  f32x4 ob0 = *(const f32x4*)(opb);
  f32x4 ob1 = *(const f32x4*)(opb + 4);
  f32x4 ob2 = *(const f32x4*)(opb + 8);
  f32x4 ob3 = *(const f32x4*)(opb + 12);
  f32x4 sA0 = {0.f,0.f,0.f,0.f}, sA1 = {0.f,0.f,0.f,0.f};
  f32x4 sA2 = {0.f,0.f,0.f,0.f}, sA3 = {0.f,0.f,0.f,0.f};
  f32x4 sB0 = {0.f,0.f,0.f,0.f}, sB1 = {0.f,0.f,0.f,0.f};
  f32x4 sB2 = {0.f,0.f,0.f,0.f}, sB3 = {0.f,0.f,0.f,0.f};

  int nbeg = split * NPB;
  const u32x4* src = (const u32x4*)(Wp16 + (size_t)nbeg * 2048);  // 16B chunks

  // staging dest for chunk e: halfs (e>>8)*2176 + ((e>>4)&15)*136 + (e&15)*8
  int e0 = t, e1 = t + 256;
  int d0 = (e0 >> 8) * 2176 + ((e0 >> 4) & 15) * 136 + (e0 & 15) * 8;
  int d1 = (e1 >> 8) * 2176 + ((e1 >> 4) & 15) * 136 + (e1 & 15) * 8;

  // prologue: stage round 0 into buf 0
  {
    u32x4 v0 = src[e0], v1 = src[e1];
    *(u32x4*)&wl[0][d0] = v0;
    *(u32x4*)&wl[0][d1] = v1;
  }
  __syncthreads();

  for (int r = 0; r < ROUNDS; r++) {
    u32x4 nv0, nv1;
    if (r < ROUNDS - 1) {
      const u32x4* s2 = src + (r + 1) * 512;
      nv0 = s2[e0]; nv1 = s2[e1];
    }
    const unsigned short* wlb = wl[r & 1];
#pragma unroll
    for (int nl = 0; nl < RN; nl++) {
      int n = nbeg + r * RN + nl;
      const float4* cpa = (const float4*)(caps + ((size_t)b0 * NCAPS + n) * 8);
      const float4* cpb = (const float4*)(caps + ((size_t)(b0 + 1) * NCAPS + n) * 8);
      float4 cqa0 = cpa[0], cqa1 = cpa[1];
      float4 cqb0 = cpb[0], cqb1 = cpb[1];
      float caA[8] = {cqa0.x, cqa0.y, cqa0.z, cqa0.w, cqa1.x, cqa1.y, cqa1.z, cqa1.w};
      float caB[8] = {cqb0.x, cqb0.y, cqb0.z, cqb0.w, cqb1.x, cqb1.y, cqb1.z, cqb1.w};
      const unsigned short* wp = wlb + nl * 2176 + o * 136;
      f32x4 xa0 = {0.f,0.f,0.f,0.f}, xa1 = {0.f,0.f,0.f,0.f};
      f32x4 xa2 = {0.f,0.f,0.f,0.f}, xa3 = {0.f,0.f,0.f,0.f};
      f32x4 xb0 = {0.f,0.f,0.f,0.f}, xb1 = {0.f,0.f,0.f,0.f};
      f32x4 xb2 = {0.f,0.f,0.f,0.f}, xb3 = {0.f,0.f,0.f,0.f};
#pragma unroll
      for (int j = 0; j < 8; j++) {
        u32x4 wA = *(const u32x4*)(wp + j * 16);
        u32x4 wB = *(const u32x4*)(wp + j * 16 + 8);
        f32x4 w0 = {BLO(wA.x), BHI(wA.x), BLO(wA.y), BHI(wA.y)};
        f32x4 w1 = {BLO(wA.z), BHI(wA.z), BLO(wA.w), BHI(wA.w)};
        f32x4 w2 = {BLO(wB.x), BHI(wB.x), BLO(wB.y), BHI(wB.y)};
        f32x4 w3 = {BLO(wB.z), BHI(wB.z), BLO(wB.w), BHI(wB.w)};
        float cjA = caA[j], cjB = caB[j];
        xa0 += w0 * cjA; xa1 += w1 * cjA; xa2 += w2 * cjA; xa3 += w3 * cjA;
        xb0 += w0 * cjB; xb1 += w1 * cjB; xb2 += w2 * cjB; xb3 += w3 * cjB;
      }
      float ccA, ccB;
      if (uniform) {
        ccA = 0.0625f; ccB = 0.0625f;
      } else {
        f32x4 pA = oa0 * xa0 + oa1 * xa1 + oa2 * xa2 + oa3 * xa3;
        f32x4 pB = ob0 * xb0 + ob1 * xb1 + ob2 * xb2 + ob3 * xb3;
        float blogA = (pA.x + pA.y) + (pA.z + pA.w);
        float blogB = (pB.x + pB.y) + (pB.z + pB.w);
        // softmax over o without max-subtract (shift-invariant; |blog| small)
        float eA = __expf(blogA);
        float eB = __expf(blogB);
        float ssA = eA, ssB = eB;
        ssA += __shfl_xor(ssA, 1); ssB += __shfl_xor(ssB, 1);
        ssA += __shfl_xor(ssA, 2); ssB += __shfl_xor(ssB, 2);
        ssA += __shfl_xor(ssA, 4); ssB += __shfl_xor(ssB, 4);
        ssA += __shfl_xor(ssA, 8); ssB += __shfl_xor(ssB, 8);
        ccA = eA * __builtin_amdgcn_rcpf(ssA);
        ccB = eB * __builtin_amdgcn_rcpf(ssB);
      }
      sA0 += xa0 * ccA; sA1 += xa1 * ccA; sA2 += xa2 * ccA; sA3 += xa3 * ccA;
      sB0 += xb0 * ccB; sB1 += xb1 * ccB; sB2 += xb2 * ccB; sB3 += xb3 * ccB;
    }
    if (r < ROUNDS - 1) {
      unsigned short* dst = wl[(r + 1) & 1];
      *(u32x4*)&dst[d0] = nv0;
      *(u32x4*)&dst[d1] = nv1;
      __syncthreads();
    }
  }
  float* spA = spart + (((size_t)split * NB + b0) * 16 + o) * 16;
  *(f32x4*)spA = sA0; *(f32x4*)(spA + 4) = sA1;
  *(f32x4*)(spA + 8) = sA2; *(f32x4*)(spA + 12) = sA3;
  float* spB = spA + 256;
  *(f32x4*)spB = sB0; *(f32x4*)(spB + 4) = sB1;
  *(f32x4*)(spB + 8) = sB2; *(f32x4*)(spB + 12) = sB3;
}

// ---------------- combine partials + squash + osum update -------------------
__global__ __launch_bounds__(256) void combine_squash_k(const float* __restrict__ spart,
    float* __restrict__ osum, float* __restrict__ outbuf, const float* __restrict__ y,
    float* __restrict__ masked, float* __restrict__ length_out, int last) {
  int tid = blockIdx.x * blockDim.x + threadIdx.x;   // 32768 = 128*16*16
  int i = tid & 15;
  int o = (tid >> 4) & 15;
  int b = tid >> 8;
  float a0 = 0.f, a1 = 0.f, a2 = 0.f, a3 = 0.f;
  int k = 0;
  for (; k + 4 <= NSPLIT; k += 4) {
    a0 += spart[(size_t)k * 32768 + tid];
    a1 += spart[(size_t)(k + 1) * 32768 + tid];
    a2 += spart[(size_t)(k + 2) * 32768 + tid];
    a3 += spart[(size_t)(k + 3) * 32768 + tid];
  }
  float s = (a0 + a1) + (a2 + a3);
  for (; k < NSPLIT; k++) s += spart[(size_t)k * 32768 + tid];
  float n2 = s * s;
#pragma unroll
  for (int d = 1; d < 16; d <<= 1) n2 += __shfl_xor(n2, d);
  float nrm = sqrtf(n2);
  float scale = n2 / (1.f + n2) / (nrm + 1e-8f);
  float ov = scale * s;
  outbuf[tid] = ov;
  osum[tid] += ov;
  if (last) {
    masked[tid] = ov * y[b * 16 + o];
    if (i == 0) length_out[b * 16 + o] = scale * nrm;
  }
}

// ---------------- decoder -----------------------------------------------------
__global__ __launch_bounds__(256) void dec1_k(const float* __restrict__ masked,
    const float* __restrict__ w1, const float* __restrict__ b1, float* __restrict__ r1) {
  int tid = blockIdx.x * blockDim.x + threadIdx.x;
  if (tid >= NB * D1) return;
  int j = tid % D1;
  int b = tid / D1;
  const float* mp = masked + b * 256;
  float acc = b1[j];
  for (int k = 0; k < 256; k++) acc += mp[k] * w1[k * D1 + j];
  r1[tid] = 1.f / (1.f + __expf(-acc));
}

__global__ __launch_bounds__(256) void dec2_k(const float* __restrict__ r1,
    const float* __restrict__ w2, const float* __restrict__ b2, float* __restrict__ r2) {
  int tid = blockIdx.x * blockDim.x + threadIdx.x;
  if (tid >= NB * D2) return;
  int j = tid % D2;
  int b = tid / D2;
  const float* rp = r1 + b * D1;
  float acc = b2[j];
  for (int k = 0; k < D1; k++) acc += rp[k] * w2[k * D2 + j];
  r2[tid] = 1.f / (1.f + __expf(-acc));
}

__global__ __launch_bounds__(256) void dec3_k(const float* __restrict__ r2,
    const float* __restrict__ w3, const float* __restrict__ b3, float* __restrict__ recon) {
  __shared__ float r2s[D2 * 64];
  int mt = blockIdx.x, bh = blockIdx.y;
  int t = threadIdx.x;
  int b0 = bh * 64;
  for (int idx = t; idx < D2 * 64; idx += 256) {
    int bb = idx / D2, k = idx - bb * D2;
    r2s[k * 64 + bb] = r2[(b0 + bb) * D2 + k];
  }
  __syncthreads();
  int moff = t & 63, bg = t >> 6;
  int m = mt * 64 + moff;
  if (m >= OUTPIX) return;
  float acc[16];
#pragma unroll
  for (int q = 0; q < 16; q++) acc[q] = 0.f;
  for (int k = 0; k < D2; k++) {
    float wv = w3[k * OUTPIX + m];
    const float4* r4 = (const float4*)&r2s[k * 64 + bg * 16];
#pragma unroll
    for (int v = 0; v < 4; v++) {
      float4 rv = r4[v];
      acc[v * 4 + 0] += wv * rv.x;
      acc[v * 4 + 1] += wv * rv.y;
      acc[v * 4 + 2] += wv * rv.z;
      acc[v * 4 + 3] += wv * rv.w;
    }
  }
  float bias = b3[m];
#pragma unroll
  for (int q = 0; q < 16; q++) {
    int b = b0 + bg * 16 + q;
    recon[(size_t)b * OUTPIX + m] = acc[q] + bias;
  }
}

extern "C" void kernel_launch(void* const* d_in, const int* in_sizes, int n_in,
                              void* d_out, int out_size, void* d_ws, size_t ws_size,
                              hipStream_t stream) {
  const float* x      = (const float*)d_in[0];
  const float* y      = (const float*)d_in[1];
  const float* conv1w = (const float*)d_in[2];
  const float* conv1b = (const float*)d_in[3];
  const float* gamma  = (const float*)d_in[4];
  const float* beta   = (const float*)d_in[5];
  const float* conv2w = (const float*)d_in[6];
  const float* conv2b = (const float*)d_in[7];
  const float* capsw  = (const float*)d_in[8];
  const float* w1     = (const float*)d_in[9];
  const float* b1     = (const float*)d_in[10];
  const float* w2     = (const float*)d_in[11];
  const float* b2     = (const float*)d_in[12];
  const float* w3     = (const float*)d_in[13];
  const float* b3     = (const float*)d_in[14];

  float* ws = (float*)d_ws;
  float* h      = ws;                    // 128*256*169   = 5537792 (dead after conv2)
  float* p      = h + 5537792;           // 3964928 (unused; kept for layout)
  float* caps   = p + 3964928;           // 128*3872*8    = 3964928
  float* mean   = caps + 3964928;        // 256
  float* istd   = mean + 256;            // 256
  float* osum   = istd + 256;            // 32768
  float* spart  = osum + 32768;          // 121*32768     = 3964928
  float* outb   = spart + 3964928;       // 32768
  float* masked = outb + 32768;          // 32768
  float* r1     = masked + 32768;        // 128*328 = 41984
  float* r2     = r1 + 41984;            // 128*192 = 24576
  unsigned short* wpk = (unsigned short*)(r2 + 24576);   // 589824 bf16
  unsigned short* wpk1 = wpk + 589824;   // 73728 bf16
  // Wp16 aliases h region (dead after conv2): 7929856 halfs = 3964928 floats
  unsigned short* Wp16 = (unsigned short*)ws;
  // hsum/hsum2 use spart region (free until routing)
  float* hsum  = spart;                  // 32768
  float* hsum2 = spart + 32768;          // 32768

  float* length_out = (float*)d_out;           // 2048
  float* recon      = (float*)d_out + 2048;    // 864000

  // conv stem (both convs via MFMA; BN fused; squash fused into conv2)
  pack_w12_k<<<(73728 + 589824) / 256, 256, 0, stream>>>(conv1w, conv2w, wpk1, wpk);
  conv1_mfma_k<<<256, 512, 0, stream>>>(x, wpk1, conv1b, h, hsum, hsum2);
  bn_finalize_k<<<2, 128, 0, stream>>>(hsum, hsum2, mean, istd);
  conv2_mfma_k<<<256, 512, 0, stream>>>(h, wpk, conv2b, caps, mean, istd, gamma, beta);

  // h dead now -> pack caps_w (bf16) into its region (exact grid: 3872*2048)
  pack_cw_k<<<7929856 / 256, 256, 0, stream>>>(capsw, Wp16);

  // dynamic routing (3 iterations), osum = sum of previous outs
  hipMemsetAsync(osum, 0, 32768 * sizeof(float), stream);
  for (int it = 0; it < 3; ++it) {
    route_k<<<484, 256, 0, stream>>>(caps, Wp16, osum, spart, it == 0 ? 1 : 0);
    combine_squash_k<<<128, 256, 0, stream>>>(spart, osum, outb, y, masked,
                                              length_out, it == 2 ? 1 : 0);
  }

  // decoder
  dec1_k<<<(NB * D1 + 255) / 256, 256, 0, stream>>>(masked, w1, b1, r1);
  dec2_k<<<(NB * D2 + 255) / 256, 256, 0, stream>>>(r1, w2, b2, r2);
  dec3_k<<<dim3((OUTPIX + 63) / 64, 2), 256, 0, stream>>>(r2, w3, b3, recon);
}

// Round 19
// 359.783 us; speedup vs baseline: 1.1179x; 1.0377x over previous
//
#include <hip/hip_runtime.h>
#include <hip/hip_bf16.h>

// Sizes
#define NB 128
#define CIN 30
#define HW 15
#define OC 256
#define H1 13   // conv1 out
#define H2 11   // conv2 out
#define NCAPS 3872
#define IND 8
#define OUTD 16
#define CLS 16
#define D1 328
#define D2 192
#define OUTPIX 6750   // 30*15*15
#define NSPLIT 121
#define NPB 32        // 121*32 = 3872 exactly
#define RN 2          // n's per LDS buffer round
#define ROUNDS 16     // NPB/RN

typedef __attribute__((ext_vector_type(8))) short short8_t;
typedef __attribute__((ext_vector_type(4))) float f32x4;
typedef __attribute__((ext_vector_type(4))) unsigned int u32x4;

__device__ inline unsigned bf16rne(float f) {
  unsigned u = __builtin_bit_cast(unsigned, f);
  return (u + 0x7FFF + ((u >> 16) & 1)) >> 16;
}

// bf16 pair (one u32) -> two exact f32
#define BLO(u) __builtin_bit_cast(float, (unsigned)((u) << 16))
#define BHI(u) __builtin_bit_cast(float, (unsigned)((u) & 0xffff0000u))

// ---------------- pack conv1+conv2 weights (merged) -------------------------
__global__ __launch_bounds__(256) void pack_w12_k(const float* __restrict__ w1,
    const float* __restrict__ w2, unsigned short* __restrict__ wpk1,
    unsigned short* __restrict__ wpk) {
  int tid = blockIdx.x * blockDim.x + threadIdx.x;   // 663552
  if (tid < 73728) {
    int j = tid & 7;
    int oc = (tid >> 3) & 255;
    int kc = (tid >> 11) & 3;
    int tap = tid >> 13;
    int ic = kc * 8 + j;
    float v = (ic < CIN) ? w1[((size_t)oc * CIN + ic) * 9 + tap] : 0.f;
    wpk1[tid] = (unsigned short)bf16rne(v);
  } else {
    int t2 = tid - 73728;                // 589824
    int e = t2 & 7;
    int oc = (t2 >> 3) & 255;
    int icchunk = (t2 >> 11) & 31;
    int kykx = t2 >> 16;
    int ic = icchunk * 8 + e;
    wpk[t2] = (unsigned short)bf16rne(w2[((size_t)oc * 256 + ic) * 9 + kykx]);
  }
}

// ---------------- conv1 via bf16 MFMA implicit GEMM + BN partial sums -------
__global__ __launch_bounds__(512, 1) void conv1_mfma_k(
    const float* __restrict__ x, const unsigned short* __restrict__ wpk1,
    const float* __restrict__ bias, float* __restrict__ h,
    float* __restrict__ hsum, float* __restrict__ hsum2) {
  __shared__ char smem[128 * 176 * 4];   // 90112 B; staging uses first 16200 B
  unsigned* hs32 = (unsigned*)smem;      // [pix][18 u32] (36 bf16, 32 data+4 pad)
  int bid = blockIdx.x;                  // 0..255
  int b = bid >> 1;
  int nh = bid & 1;
  int t = threadIdx.x;
  int l = t & 63;
  int wid = t >> 6;

  if (t < 225) {
    const float* xb = x + (size_t)b * (CIN * 225);
#pragma unroll
    for (int icp = 0; icp < 15; icp++) {
      unsigned u0 = bf16rne(xb[(2 * icp) * 225 + t]);
      unsigned u1 = bf16rne(xb[(2 * icp + 1) * 225 + t]);
      hs32[t * 18 + icp] = u0 | (u1 << 16);
    }
    hs32[t * 18 + 15] = 0;               // ic 30,31 zero pad
  }
  __syncthreads();

  int row = l & 15, kc = l >> 4;
  int ocb = nh * 128 + wid * 16;

  int arow[11];
#pragma unroll
  for (int mf = 0; mf < 11; mf++) {
    int m = mf * 16 + row;
    int pix = 0;
    if (m < 169) { int oy = m / 13, ox = m - oy * 13; pix = oy * HW + ox; }
    arow[mf] = pix * 72 + kc * 16;
  }

  f32x4 acc[11];
#pragma unroll
  for (int mf = 0; mf < 11; mf++) acc[mf] = (f32x4){0.f, 0.f, 0.f, 0.f};

  const size_t lanebase = ((size_t)ocb + row) * 8;
  const char* lds_base = (const char*)smem;

#pragma unroll
  for (int tap = 0; tap < 9; tap++) {
    const int ky = tap / 3, kx = tap % 3;
    const int koff = (ky * HW + kx) * 72;
    short8_t bfr = *(const short8_t*)(wpk1 + (size_t)(tap * 4 + kc) * 2048 + lanebase);
#pragma unroll
    for (int mf = 0; mf < 11; mf++) {
      short8_t af = *(const short8_t*)(lds_base + arow[mf] + koff);
      acc[mf] = __builtin_amdgcn_mfma_f32_16x16x32_bf16(af, bfr, acc[mf], 0, 0, 0);
    }
  }

  __syncthreads();
  float* cl = (float*)smem;              // [ocl 128][176 m-pad]
  {
    int ocl = wid * 16 + row;
#pragma unroll
    for (int mf = 0; mf < 11; mf++) {
      int m0 = mf * 16 + kc * 4;
      *(f32x4*)&cl[ocl * 176 + m0] = acc[mf];
    }
  }
  __syncthreads();
  for (int idx = t; idx < 128 * 169; idx += 512) {
    int ocl = idx / 169;
    int m = idx - ocl * 169;
    int oc = nh * 128 + ocl;
    h[((size_t)b * 256 + oc) * 169 + m] = cl[ocl * 176 + m] + bias[oc];
  }
  // BN partial sums per (b, oc): deterministic fixed-order reduction
  {
    int ocl = t >> 2, sub = t & 3;
    float bs = bias[nh * 128 + ocl];
    float s1 = 0.f, s2 = 0.f;
    int m0 = sub * 43, m1 = m0 + 43; if (m1 > 169) m1 = 169;
    for (int m = m0; m < m1; m++) {
      float v = cl[ocl * 176 + m] + bs;
      s1 += v; s2 += v * v;
    }
    s1 += __shfl_xor(s1, 1); s2 += __shfl_xor(s2, 1);
    s1 += __shfl_xor(s1, 2); s2 += __shfl_xor(s2, 2);
    if (sub == 0) {
      hsum[b * 256 + nh * 128 + ocl] = s1;
      hsum2[b * 256 + nh * 128 + ocl] = s2;
    }
  }
}

// ---------------- BN finalize: reduce 128 b-partials per channel ------------
__global__ __launch_bounds__(128) void bn_finalize_k(const float* __restrict__ hsum,
    const float* __restrict__ hsum2, float* __restrict__ mean, float* __restrict__ istd) {
  int c = blockIdx.x * 128 + threadIdx.x;   // 2 blocks x 128
  float s = 0.f, s2 = 0.f;
  for (int b = 0; b < NB; b++) {
    s += hsum[b * 256 + c];
    s2 += hsum2[b * 256 + c];
  }
  const float inv_n = 1.0f / (NB * H1 * H1);
  float m = s * inv_n;
  float v = s2 * inv_n - m * m;
  mean[c] = m;
  istd[c] = rsqrtf(v + 1e-5f);
}

// ---------------- conv2 via bf16 MFMA (BN+relu fused in; squash fused out) --
__global__ __launch_bounds__(512, 1) void conv2_mfma_k(
    const float* __restrict__ h, const unsigned short* __restrict__ wpk,
    const float* __restrict__ bias, float* __restrict__ caps,
    const float* __restrict__ mean, const float* __restrict__ istd,
    const float* __restrict__ gamma, const float* __restrict__ beta) {
  __shared__ char smem[169 * 544];       // 91936 B; reused for C transpose
  unsigned* hs32 = (unsigned*)smem;      // [pix][136] u32  (272 bf16, 16 pad)
  int bid = blockIdx.x;                  // 0..255
  int b = bid >> 1;
  int nh = bid & 1;                      // oc half
  int t = threadIdx.x;
  int l = t & 63, wid = t >> 6;

  {
    const float* hb = h + (size_t)b * 256 * 169;
    for (int icp = wid; icp < 128; icp += 8) {
      const float* s0 = hb + (size_t)icp * 2 * 169;
      int c0i = icp * 2, c1i = icp * 2 + 1;
      float a0 = istd[c0i] * gamma[c0i], sh0 = beta[c0i] - mean[c0i] * a0;
      float a1 = istd[c1i] * gamma[c1i], sh1 = beta[c1i] - mean[c1i] * a1;
#pragma unroll
      for (int pb = 0; pb < 3; pb++) {
        int pix = pb * 64 + l;
        if (pix < 169) {
          float v0 = fmaxf(fmaf(s0[pix], a0, sh0), 0.f);
          float v1 = fmaxf(fmaf(s0[169 + pix], a1, sh1), 0.f);
          hs32[pix * 136 + icp] = bf16rne(v0) | (bf16rne(v1) << 16);
        }
      }
    }
  }
  __syncthreads();

  int wm = wid & 1;        // m offset wm*64
  int wn = wid >> 1;       // n offset wn*32
  int row = l & 15, kc = l >> 4;
  int ocb = nh * 128 + wn * 32;

  int abase[4];
#pragma unroll
  for (int mf = 0; mf < 4; mf++) {
    int m = wm * 64 + mf * 16 + row;
    int p0 = (m < 121) ? ((m / 11) * 13 + (m % 11)) : 0;
    abase[mf] = p0 * 544 + kc * 16;
  }

  f32x4 acc[4][2];
#pragma unroll
  for (int mf = 0; mf < 4; mf++)
#pragma unroll
    for (int nf = 0; nf < 2; nf++)
      acc[mf][nf] = (f32x4){0.f, 0.f, 0.f, 0.f};

  const size_t lanebase = ((size_t)kc * 256 + ocb + row) * 8;
  const char* lds_base = (const char*)smem;

  for (int ky = 0; ky < 3; ky++) {
    for (int kx = 0; kx < 3; kx++) {
      int r = ky * 3 + kx;
      int koff = (ky * 13 + kx) * 544;
#pragma unroll
      for (int ks = 0; ks < 8; ks++) {
        short8_t bfr[2];
#pragma unroll
        for (int nf = 0; nf < 2; nf++) {
          size_t idx = lanebase + (size_t)(r * 32 + ks * 4) * 2048 + nf * 128;
          bfr[nf] = *(const short8_t*)(wpk + idx);
        }
        short8_t af[4];
#pragma unroll
        for (int mf = 0; mf < 4; mf++)
          af[mf] = *(const short8_t*)(lds_base + (abase[mf] + koff + ks * 64));
#pragma unroll
        for (int mf = 0; mf < 4; mf++)
#pragma unroll
          for (int nf = 0; nf < 2; nf++)
            acc[mf][nf] = __builtin_amdgcn_mfma_f32_16x16x32_bf16(
                af[mf], bfr[nf], acc[mf][nf], 0, 0, 0);
      }
    }
  }

  __syncthreads();
  float* cl = (float*)smem;              // [ocl 0..127][132 m-pad]
#pragma unroll
  for (int nf = 0; nf < 2; nf++) {
    int ocl = wn * 32 + nf * 16 + row;
#pragma unroll
    for (int mf = 0; mf < 4; mf++) {
      int m0 = wm * 64 + mf * 16 + kc * 4;
      f32x4 v = acc[mf][nf];
      *(f32x4*)&cl[ocl * 132 + m0] = v;
    }
  }
  __syncthreads();
  // fused squash: groups of 8 over flat [128 oc][121 pix] (+bias) -> caps
  for (int g = t; g < 1936; g += 512) {
    int base = g * 8;
    float v[8];
    float n2 = 0.f;
#pragma unroll
    for (int e = 0; e < 8; e++) {
      int idx = base + e;
      int q = idx / 121, rmd = idx - q * 121;
      float val = cl[q * 132 + rmd] + bias[nh * 128 + q];
      v[e] = val;
      n2 += val * val;
    }
    float nrm = sqrtf(n2);
    float scale = n2 / (1.f + n2) / (nrm + 1e-8f);
    float4 o0 = {v[0] * scale, v[1] * scale, v[2] * scale, v[3] * scale};
    float4 o1 = {v[4] * scale, v[5] * scale, v[6] * scale, v[7] * scale};
    float4* dst = (float4*)(caps + (((size_t)b * NCAPS) + nh * 1936 + g) * 8);
    dst[0] = o0; dst[1] = o1;
  }
}

// ---------------- pack caps_w: cw[o][n][i][j] -> Wp16[n][o][j][i] bf16 ------
__global__ __launch_bounds__(256) void pack_cw_k(const float* __restrict__ cw,
    unsigned short* __restrict__ Wp16) {
  int idx = blockIdx.x * blockDim.x + threadIdx.x;   // 7929856 = 3872*2048 exact
  int i = idx & 15;
  int j = (idx >> 4) & 7;
  int o = (idx >> 7) & 15;
  int n = idx >> 11;
  Wp16[idx] = (unsigned short)bf16rne(cw[(((size_t)o * NCAPS + n) * 16 + i) * 8 + j]);
}

// ---------------- routing pass 0: uniform coeffs (osum==0 -> c==1/16) -------
// Separate kernel so the hot route_k codegen is untouched. Accumulates raw
// sums, scales by 1/16 once at writeout.
__global__ __launch_bounds__(256) void route0_k(const float* __restrict__ caps,
    const unsigned short* __restrict__ Wp16, float* __restrict__ spart) {
  __shared__ unsigned short wl[2][RN * 2176];   // 17408 B
  int id = blockIdx.x;                     // 0..483
  int xcd = id & 7;
  int lin = (xcd < 4 ? xcd * 61 : 244 + (xcd - 4) * 60) + (id >> 3);
  int split = lin >> 2;                    // 0..120
  int btile = lin & 3;                     // 0..3
  int t = threadIdx.x;                     // 0..255
  int o = t & 15;
  int bp = t >> 4;                         // 0..15
  int b0 = btile * 32 + bp * 2;

  f32x4 sA0 = {0.f,0.f,0.f,0.f}, sA1 = {0.f,0.f,0.f,0.f};
  f32x4 sA2 = {0.f,0.f,0.f,0.f}, sA3 = {0.f,0.f,0.f,0.f};
  f32x4 sB0 = {0.f,0.f,0.f,0.f}, sB1 = {0.f,0.f,0.f,0.f};
  f32x4 sB2 = {0.f,0.f,0.f,0.f}, sB3 = {0.f,0.f,0.f,0.f};

  int nbeg = split * NPB;
  const u32x4* src = (const u32x4*)(Wp16 + (size_t)nbeg * 2048);

  int e0 = t, e1 = t + 256;
  int d0 = (e0 >> 8) * 2176 + ((e0 >> 4) & 15) * 136 + (e0 & 15) * 8;
  int d1 = (e1 >> 8) * 2176 + ((e1 >> 4) & 15) * 136 + (e1 & 15) * 8;

  {
    u32x4 v0 = src[e0], v1 = src[e1];
    *(u32x4*)&wl[0][d0] = v0;
    *(u32x4*)&wl[0][d1] = v1;
  }
  __syncthreads();

  for (int r = 0; r < ROUNDS; r++) {
    u32x4 nv0, nv1;
    if (r < ROUNDS - 1) {
      const u32x4* s2 = src + (r + 1) * 512;
      nv0 = s2[e0]; nv1 = s2[e1];
    }
    const unsigned short* wlb = wl[r & 1];
#pragma unroll
    for (int nl = 0; nl < RN; nl++) {
      int n = nbeg + r * RN + nl;
      const float4* cpa = (const float4*)(caps + ((size_t)b0 * NCAPS + n) * 8);
      const float4* cpb = (const float4*)(caps + ((size_t)(b0 + 1) * NCAPS + n) * 8);
      float4 cqa0 = cpa[0], cqa1 = cpa[1];
      float4 cqb0 = cpb[0], cqb1 = cpb[1];
      float caA[8] = {cqa0.x, cqa0.y, cqa0.z, cqa0.w, cqa1.x, cqa1.y, cqa1.z, cqa1.w};
      float caB[8] = {cqb0.x, cqb0.y, cqb0.z, cqb0.w, cqb1.x, cqb1.y, cqb1.z, cqb1.w};
      const unsigned short* wp = wlb + nl * 2176 + o * 136;
#pragma unroll
      for (int j = 0; j < 8; j++) {
        u32x4 wA = *(const u32x4*)(wp + j * 16);
        u32x4 wB = *(const u32x4*)(wp + j * 16 + 8);
        f32x4 w0 = {BLO(wA.x), BHI(wA.x), BLO(wA.y), BHI(wA.y)};
        f32x4 w1 = {BLO(wA.z), BHI(wA.z), BLO(wA.w), BHI(wA.w)};
        f32x4 w2 = {BLO(wB.x), BHI(wB.x), BLO(wB.y), BHI(wB.y)};
        f32x4 w3 = {BLO(wB.z), BHI(wB.z), BLO(wB.w), BHI(wB.w)};
        float cjA = caA[j], cjB = caB[j];
        sA0 += w0 * cjA; sA1 += w1 * cjA; sA2 += w2 * cjA; sA3 += w3 * cjA;
        sB0 += w0 * cjB; sB1 += w1 * cjB; sB2 += w2 * cjB; sB3 += w3 * cjB;
      }
    }
    if (r < ROUNDS - 1) {
      unsigned short* dst = wl[(r + 1) & 1];
      *(u32x4*)&dst[d0] = nv0;
      *(u32x4*)&dst[d1] = nv1;
      __syncthreads();
    }
  }
  const float c16 = 0.0625f;
  float* spA = spart + (((size_t)split * NB + b0) * 16 + o) * 16;
  *(f32x4*)spA = sA0 * c16; *(f32x4*)(spA + 4) = sA1 * c16;
  *(f32x4*)(spA + 8) = sA2 * c16; *(f32x4*)(spA + 12) = sA3 * c16;
  float* spB = spA + 256;
  *(f32x4*)spB = sB0 * c16; *(f32x4*)(spB + 4) = sB1 * c16;
  *(f32x4*)(spB + 8) = sB2 * c16; *(f32x4*)(spB + 12) = sB3 * c16;
}

// ---------------- routing pass (r14 champion body, untouched) ---------------
__global__ __launch_bounds__(256) void route_k(const float* __restrict__ caps,
    const unsigned short* __restrict__ Wp16, const float* __restrict__ osum,
    float* __restrict__ spart) {
  __shared__ unsigned short wl[2][RN * 2176];   // 17408 B
  int id = blockIdx.x;                     // 0..483
  // bijective chunked XCD swizzle (484 = 4 chunks of 61 + 4 of 60):
  int xcd = id & 7;
  int lin = (xcd < 4 ? xcd * 61 : 244 + (xcd - 4) * 60) + (id >> 3);
  int split = lin >> 2;                    // 0..120
  int btile = lin & 3;                     // 0..3
  int t = threadIdx.x;                     // 0..255
  int o = t & 15;
  int bp = t >> 4;                         // 0..15
  int b0 = btile * 32 + bp * 2;            // this thread: b0 and b0+1

  const float* opa = osum + (b0 * 16 + o) * 16;
  f32x4 oa0 = *(const f32x4*)(opa);
  f32x4 oa1 = *(const f32x4*)(opa + 4);
  f32x4 oa2 = *(const f32x4*)(opa + 8);
  f32x4 oa3 = *(const f32x4*)(opa + 12);
  const float* opb = opa + 256;
  f32x4 ob0 = *(const f32x4*)(opb);
  f32x4 ob1 = *(const f32x4*)(opb + 4);
  f32x4 ob2 = *(const f32x4*)(opb + 8);
  f32x4 ob3 = *(const f32x4*)(opb + 12);
  f32x4 sA0 = {0.f,0.f,0.f,0.f}, sA1 = {0.f,0.f,0.f,0.f};
  f32x4 sA2 = {0.f,0.f,0.f,0.f}, sA3 = {0.f,0.f,0.f,0.f};
  f32x4 sB0 = {0.f,0.f,0.f,0.f}, sB1 = {0.f,0.f,0.f,0.f};
  f32x4 sB2 = {0.f,0.f,0.f,0.f}, sB3 = {0.f,0.f,0.f,0.f};

  int nbeg = split * NPB;
  const u32x4* src = (const u32x4*)(Wp16 + (size_t)nbeg * 2048);  // 16B chunks

  // staging dest for chunk e: halfs (e>>8)*2176 + ((e>>4)&15)*136 + (e&15)*8
  int e0 = t, e1 = t + 256;
  int d0 = (e0 >> 8) * 2176 + ((e0 >> 4) & 15) * 136 + (e0 & 15) * 8;
  int d1 = (e1 >> 8) * 2176 + ((e1 >> 4) & 15) * 136 + (e1 & 15) * 8;

  // prologue: stage round 0 into buf 0
  {
    u32x4 v0 = src[e0], v1 = src[e1];
    *(u32x4*)&wl[0][d0] = v0;
    *(u32x4*)&wl[0][d1] = v1;
  }
  __syncthreads();

  for (int r = 0; r < ROUNDS; r++) {
    u32x4 nv0, nv1;
    if (r < ROUNDS - 1) {
      const u32x4* s2 = src + (r + 1) * 512;
      nv0 = s2[e0]; nv1 = s2[e1];
    }
    const unsigned short* wlb = wl[r & 1];
#pragma unroll
    for (int nl = 0; nl < RN; nl++) {
      int n = nbeg + r * RN + nl;
      const float4* cpa = (const float4*)(caps + ((size_t)b0 * NCAPS + n) * 8);
      const float4* cpb = (const float4*)(caps + ((size_t)(b0 + 1) * NCAPS + n) * 8);
      float4 cqa0 = cpa[0], cqa1 = cpa[1];
      float4 cqb0 = cpb[0], cqb1 = cpb[1];
      float caA[8] = {cqa0.x, cqa0.y, cqa0.z, cqa0.w, cqa1.x, cqa1.y, cqa1.z, cqa1.w};
      float caB[8] = {cqb0.x, cqb0.y, cqb0.z, cqb0.w, cqb1.x, cqb1.y, cqb1.z, cqb1.w};
      const unsigned short* wp = wlb + nl * 2176 + o * 136;
      f32x4 xa0 = {0.f,0.f,0.f,0.f}, xa1 = {0.f,0.f,0.f,0.f};
      f32x4 xa2 = {0.f,0.f,0.f,0.f}, xa3 = {0.f,0.f,0.f,0.f};
      f32x4 xb0 = {0.f,0.f,0.f,0.f}, xb1 = {0.f,0.f,0.f,0.f};
      f32x4 xb2 = {0.f,0.f,0.f,0.f}, xb3 = {0.f,0.f,0.f,0.f};
#pragma unroll
      for (int j = 0; j < 8; j++) {
        u32x4 wA = *(const u32x4*)(wp + j * 16);
        u32x4 wB = *(const u32x4*)(wp + j * 16 + 8);
        f32x4 w0 = {BLO(wA.x), BHI(wA.x), BLO(wA.y), BHI(wA.y)};
        f32x4 w1 = {BLO(wA.z), BHI(wA.z), BLO(wA.w), BHI(wA.w)};
        f32x4 w2 = {BLO(wB.x), BHI(wB.x), BLO(wB.y), BHI(wB.y)};
        f32x4 w3 = {BLO(wB.z), BHI(wB.z), BLO(wB.w), BHI(wB.w)};
        float cjA = caA[j], cjB = caB[j];
        xa0 += w0 * cjA; xa1 += w1 * cjA; xa2 += w2 * cjA; xa3 += w3 * cjA;
        xb0 += w0 * cjB; xb1 += w1 * cjB; xb2 += w2 * cjB; xb3 += w3 * cjB;
      }
      f32x4 pA = oa0 * xa0 + oa1 * xa1 + oa2 * xa2 + oa3 * xa3;
      f32x4 pB = ob0 * xb0 + ob1 * xb1 + ob2 * xb2 + ob3 * xb3;
      float blogA = (pA.x + pA.y) + (pA.z + pA.w);
      float blogB = (pB.x + pB.y) + (pB.z + pB.w);
      // softmax over o without max-subtract (shift-invariant; |blog| small)
      float eA = __expf(blogA);
      float eB = __expf(blogB);
      float ssA = eA, ssB = eB;
      ssA += __shfl_xor(ssA, 1); ssB += __shfl_xor(ssB, 1);
      ssA += __shfl_xor(ssA, 2); ssB += __shfl_xor(ssB, 2);
      ssA += __shfl_xor(ssA, 4); ssB += __shfl_xor(ssB, 4);
      ssA += __shfl_xor(ssA, 8); ssB += __shfl_xor(ssB, 8);
      float ccA = eA * __builtin_amdgcn_rcpf(ssA);
      float ccB = eB * __builtin_amdgcn_rcpf(ssB);
      sA0 += xa0 * ccA; sA1 += xa1 * ccA; sA2 += xa2 * ccA; sA3 += xa3 * ccA;
      sB0 += xb0 * ccB; sB1 += xb1 * ccB; sB2 += xb2 * ccB; sB3 += xb3 * ccB;
    }
    if (r < ROUNDS - 1) {
      unsigned short* dst = wl[(r + 1) & 1];
      *(u32x4*)&dst[d0] = nv0;
      *(u32x4*)&dst[d1] = nv1;
      __syncthreads();
    }
  }
  float* spA = spart + (((size_t)split * NB + b0) * 16 + o) * 16;
  *(f32x4*)spA = sA0; *(f32x4*)(spA + 4) = sA1;
  *(f32x4*)(spA + 8) = sA2; *(f32x4*)(spA + 12) = sA3;
  float* spB = spA + 256;
  *(f32x4*)spB = sB0; *(f32x4*)(spB + 4) = sB1;
  *(f32x4*)(spB + 8) = sB2; *(f32x4*)(spB + 12) = sB3;
}

// ---------------- combine partials + squash + osum update -------------------
__global__ __launch_bounds__(256) void combine_squash_k(const float* __restrict__ spart,
    float* __restrict__ osum, float* __restrict__ outbuf, const float* __restrict__ y,
    float* __restrict__ masked, float* __restrict__ length_out, int last) {
  int tid = blockIdx.x * blockDim.x + threadIdx.x;   // 32768 = 128*16*16
  int i = tid & 15;
  int o = (tid >> 4) & 15;
  int b = tid >> 8;
  float a0 = 0.f, a1 = 0.f, a2 = 0.f, a3 = 0.f;
  int k = 0;
  for (; k + 4 <= NSPLIT; k += 4) {
    a0 += spart[(size_t)k * 32768 + tid];
    a1 += spart[(size_t)(k + 1) * 32768 + tid];
    a2 += spart[(size_t)(k + 2) * 32768 + tid];
    a3 += spart[(size_t)(k + 3) * 32768 + tid];
  }
  float s = (a0 + a1) + (a2 + a3);
  for (; k < NSPLIT; k++) s += spart[(size_t)k * 32768 + tid];
  float n2 = s * s;
#pragma unroll
  for (int d = 1; d < 16; d <<= 1) n2 += __shfl_xor(n2, d);
  float nrm = sqrtf(n2);
  float scale = n2 / (1.f + n2) / (nrm + 1e-8f);
  float ov = scale * s;
  outbuf[tid] = ov;
  osum[tid] += ov;
  if (last) {
    masked[tid] = ov * y[b * 16 + o];
    if (i == 0) length_out[b * 16 + o] = scale * nrm;
  }
}

// ---------------- decoder -----------------------------------------------------
__global__ __launch_bounds__(256) void dec1_k(const float* __restrict__ masked,
    const float* __restrict__ w1, const float* __restrict__ b1, float* __restrict__ r1) {
  int tid = blockIdx.x * blockDim.x + threadIdx.x;
  if (tid >= NB * D1) return;
  int j = tid % D1;
  int b = tid / D1;
  const float* mp = masked + b * 256;
  float acc = b1[j];
  for (int k = 0; k < 256; k++) acc += mp[k] * w1[k * D1 + j];
  r1[tid] = 1.f / (1.f + __expf(-acc));
}

__global__ __launch_bounds__(256) void dec2_k(const float* __restrict__ r1,
    const float* __restrict__ w2, const float* __restrict__ b2, float* __restrict__ r2) {
  int tid = blockIdx.x * blockDim.x + threadIdx.x;
  if (tid >= NB * D2) return;
  int j = tid % D2;
  int b = tid / D2;
  const float* rp = r1 + b * D1;
  float acc = b2[j];
  for (int k = 0; k < D1; k++) acc += rp[k] * w2[k * D2 + j];
  r2[tid] = 1.f / (1.f + __expf(-acc));
}

__global__ __launch_bounds__(256) void dec3_k(const float* __restrict__ r2,
    const float* __restrict__ w3, const float* __restrict__ b3, float* __restrict__ recon) {
  __shared__ float r2s[D2 * 64];
  int mt = blockIdx.x, bh = blockIdx.y;
  int t = threadIdx.x;
  int b0 = bh * 64;
  for (int idx = t; idx < D2 * 64; idx += 256) {
    int bb = idx / D2, k = idx - bb * D2;
    r2s[k * 64 + bb] = r2[(b0 + bb) * D2 + k];
  }
  __syncthreads();
  int moff = t & 63, bg = t >> 6;
  int m = mt * 64 + moff;
  if (m >= OUTPIX) return;
  float acc[16];
#pragma unroll
  for (int q = 0; q < 16; q++) acc[q] = 0.f;
  for (int k = 0; k < D2; k++) {
    float wv = w3[k * OUTPIX + m];
    const float4* r4 = (const float4*)&r2s[k * 64 + bg * 16];
#pragma unroll
    for (int v = 0; v < 4; v++) {
      float4 rv = r4[v];
      acc[v * 4 + 0] += wv * rv.x;
      acc[v * 4 + 1] += wv * rv.y;
      acc[v * 4 + 2] += wv * rv.z;
      acc[v * 4 + 3] += wv * rv.w;
    }
  }
  float bias = b3[m];
#pragma unroll
  for (int q = 0; q < 16; q++) {
    int b = b0 + bg * 16 + q;
    recon[(size_t)b * OUTPIX + m] = acc[q] + bias;
  }
}

extern "C" void kernel_launch(void* const* d_in, const int* in_sizes, int n_in,
                              void* d_out, int out_size, void* d_ws, size_t ws_size,
                              hipStream_t stream) {
  const float* x      = (const float*)d_in[0];
  const float* y      = (const float*)d_in[1];
  const float* conv1w = (const float*)d_in[2];
  const float* conv1b = (const float*)d_in[3];
  const float* gamma  = (const float*)d_in[4];
  const float* beta   = (const float*)d_in[5];
  const float* conv2w = (const float*)d_in[6];
  const float* conv2b = (const float*)d_in[7];
  const float* capsw  = (const float*)d_in[8];
  const float* w1     = (const float*)d_in[9];
  const float* b1     = (const float*)d_in[10];
  const float* w2     = (const float*)d_in[11];
  const float* b2     = (const float*)d_in[12];
  const float* w3     = (const float*)d_in[13];
  const float* b3     = (const float*)d_in[14];

  float* ws = (float*)d_ws;
  float* h      = ws;                    // 128*256*169   = 5537792 (dead after conv2)
  float* p      = h + 5537792;           // 3964928 (unused; kept for layout)
  float* caps   = p + 3964928;           // 128*3872*8    = 3964928
  float* mean   = caps + 3964928;        // 256
  float* istd   = mean + 256;            // 256
  float* osum   = istd + 256;            // 32768
  float* spart  = osum + 32768;          // 121*32768     = 3964928
  float* outb   = spart + 3964928;       // 32768
  float* masked = outb + 32768;          // 32768
  float* r1     = masked + 32768;        // 128*328 = 41984
  float* r2     = r1 + 41984;            // 128*192 = 24576
  unsigned short* wpk = (unsigned short*)(r2 + 24576);   // 589824 bf16
  unsigned short* wpk1 = wpk + 589824;   // 73728 bf16
  // Wp16 aliases h region (dead after conv2): 7929856 halfs = 3964928 floats
  unsigned short* Wp16 = (unsigned short*)ws;
  // hsum/hsum2 use spart region (free until routing)
  float* hsum  = spart;                  // 32768
  float* hsum2 = spart + 32768;          // 32768

  float* length_out = (float*)d_out;           // 2048
  float* recon      = (float*)d_out + 2048;    // 864000

  // conv stem (both convs via MFMA; BN fused; squash fused into conv2)
  pack_w12_k<<<(73728 + 589824) / 256, 256, 0, stream>>>(conv1w, conv2w, wpk1, wpk);
  conv1_mfma_k<<<256, 512, 0, stream>>>(x, wpk1, conv1b, h, hsum, hsum2);
  bn_finalize_k<<<2, 128, 0, stream>>>(hsum, hsum2, mean, istd);
  conv2_mfma_k<<<256, 512, 0, stream>>>(h, wpk, conv2b, caps, mean, istd, gamma, beta);

  // h dead now -> pack caps_w (bf16) into its region (exact grid: 3872*2048)
  pack_cw_k<<<7929856 / 256, 256, 0, stream>>>(capsw, Wp16);

  // dynamic routing: it0 uses uniform-coeff kernel (osum==0 -> c==1/16);
  // its 1-2 use the champion full kernel. osum zero-init still needed for
  // combine's osum accumulation.
  hipMemsetAsync(osum, 0, 32768 * sizeof(float), stream);
  route0_k<<<484, 256, 0, stream>>>(caps, Wp16, spart);
  combine_squash_k<<<128, 256, 0, stream>>>(spart, osum, outb, y, masked,
                                            length_out, 0);
  for (int it = 1; it < 3; ++it) {
    route_k<<<484, 256, 0, stream>>>(caps, Wp16, osum, spart);
    combine_squash_k<<<128, 256, 0, stream>>>(spart, osum, outb, y, masked,
                                              length_out, it == 2 ? 1 : 0);
  }

  // decoder
  dec1_k<<<(NB * D1 + 255) / 256, 256, 0, stream>>>(masked, w1, b1, r1);
  dec2_k<<<(NB * D2 + 255) / 256, 256, 0, stream>>>(r1, w2, b2, r2);
  dec3_k<<<dim3((OUTPIX + 63) / 64, 2), 256, 0, stream>>>(r2, w3, b3, recon);
}